// Round 1
// baseline (2435.050 us; speedup 1.0000x reference)
//
#include <hip/hip_runtime.h>

// Problem constants (from reference).
constexpr int NN  = 50000;   // nodes
constexpr int NE  = 150000;  // edges
constexpr int IN  = 16;
constexpr int HID = 32;
constexpr int LAT = 16;
constexpr int EF  = 8;       // edge feature dim
constexpr int HE  = 128;     // edge-MLP hidden dim

// ---------------------------------------------------------------------------
// in-degree counts (float, for the mean normalization of c1/c2)
// ---------------------------------------------------------------------------
__global__ void count_kernel(const int* __restrict__ dst, float* __restrict__ cnt) {
  int e = blockIdx.x * blockDim.x + threadIdx.x;
  if (e < NE) atomicAdd(&cnt[dst[e]], 1.0f);
}

// ---------------------------------------------------------------------------
// Hot kernel: per-edge  h = relu(ea@w1+b1);  W = h@w2+b2 (implicit);
//             msg = x[src] @ W;  atomicAdd into agg[dst].
// One thread per edge. msg + x row live in registers; w2/w1/b1 accesses are
// wave-uniform -> scalar loads / L1 broadcast.
// ---------------------------------------------------------------------------
template <int DIN, int DOUT>
__launch_bounds__(64)
__global__ void nnconv_edges(const float* __restrict__ xin,   // [NN, DIN]
                             const int*   __restrict__ src,   // [NE]
                             const int*   __restrict__ dst,   // [NE]
                             const float* __restrict__ ea,    // [NE, EF]
                             const float* __restrict__ w1,    // [EF, HE]
                             const float* __restrict__ b1,    // [HE]
                             const float* __restrict__ w2,    // [HE, DIN*DOUT]
                             const float* __restrict__ b2,    // [DIN*DOUT]
                             float* __restrict__ agg)         // [NN, DOUT]
{
  const int e = blockIdx.x * blockDim.x + threadIdx.x;
  if (e >= NE) return;

  float eav[EF];
#pragma unroll
  for (int i = 0; i < EF; i++) eav[i] = ea[(long)e * EF + i];

  const int s = src[e];
  float xv[DIN];
#pragma unroll
  for (int i = 0; i < DIN; i++) xv[i] = xin[(long)s * DIN + i];

  float msg[DOUT];
#pragma unroll
  for (int o = 0; o < DOUT; o++) msg[o] = 0.0f;

#pragma unroll 1
  for (int k = 0; k < HE; k++) {
    // h_k = relu(b1[k] + ea . w1[:,k])
    float hk = b1[k];
#pragma unroll
    for (int i = 0; i < EF; i++) hk = fmaf(eav[i], w1[i * HE + k], hk);
    hk = fmaxf(hk, 0.0f);

    const float* __restrict__ w2k = w2 + (long)k * (DIN * DOUT);
#pragma unroll
    for (int i = 0; i < DIN; i++) {
      const float xh = xv[i] * hk;
#pragma unroll
      for (int o = 0; o < DOUT; o++)
        msg[o] = fmaf(xh, w2k[i * DOUT + o], msg[o]);
    }
  }

  // b2 contribution: msg += x . reshape(b2, [DIN, DOUT])
#pragma unroll
  for (int i = 0; i < DIN; i++)
#pragma unroll
    for (int o = 0; o < DOUT; o++)
      msg[o] = fmaf(xv[i], b2[i * DOUT + o], msg[o]);

  const int d = dst[e];
  const long base = (long)d * DOUT;
#pragma unroll
  for (int o = 0; o < DOUT; o++) atomicAdd(&agg[base + o], msg[o]);
}

// ---------------------------------------------------------------------------
// Epilogue: out = agg (/ max(cnt,1) if MEAN) + x@root + bias; optional relu.
// One thread per node.
// ---------------------------------------------------------------------------
template <int DIN, int DOUT, bool MEAN, bool RELU>
__launch_bounds__(256)
__global__ void finish_kernel(const float* __restrict__ agg,   // [NN, DOUT]
                              const float* __restrict__ cnt,   // [NN]
                              const float* __restrict__ xin,   // [NN, DIN]
                              const float* __restrict__ root,  // [DIN, DOUT]
                              const float* __restrict__ bias,  // [DOUT]
                              float* __restrict__ out)         // [NN, DOUT]
{
  const int n = blockIdx.x * blockDim.x + threadIdx.x;
  if (n >= NN) return;

  float xv[DIN];
#pragma unroll
  for (int i = 0; i < DIN; i++) xv[i] = xin[(long)n * DIN + i];

  const float inv = MEAN ? (1.0f / fmaxf(cnt[n], 1.0f)) : 1.0f;

#pragma unroll
  for (int o = 0; o < DOUT; o++) {
    float v = agg[(long)n * DOUT + o] * inv + bias[o];
#pragma unroll
    for (int i = 0; i < DIN; i++) v = fmaf(xv[i], root[i * DOUT + o], v);
    if (RELU) v = fmaxf(v, 0.0f);
    out[(long)n * DOUT + o] = v;
  }
}

// ---------------------------------------------------------------------------
extern "C" void kernel_launch(void* const* d_in, const int* in_sizes, int n_in,
                              void* d_out, int out_size, void* d_ws, size_t ws_size,
                              hipStream_t stream) {
  const float* x  = (const float*)d_in[0];
  const int*   ei = (const int*)d_in[1];
  const float* ea = (const float*)d_in[2];
  const int* src = ei;        // edge_index[0, :]
  const int* dst = ei + NE;   // edge_index[1, :]

  // per-conv params: 3 + c*6 + {w1,b1,w2,b2,root,bias}
  auto P = [&](int c, int j) -> const float* {
    return (const float*)d_in[3 + c * 6 + j];
  };

  float* ws  = (float*)d_ws;
  float* cnt = ws;                              // NN
  float* h1  = cnt + NN;                        // NN*HID
  float* h2  = h1 + (size_t)NN * HID;           // NN*HID
  float* agg = h2 + (size_t)NN * HID;           // NN*HID (reused per conv)

  float* out_mu = (float*)d_out;
  float* out_lv = out_mu + (size_t)NN * LAT;

  const int EB = 64;
  const dim3 egrid((NE + EB - 1) / EB), eblk(EB);
  const dim3 ngrid((NN + 255) / 256), nblk(256);

  // degree counts (same for all convs)
  hipMemsetAsync(cnt, 0, (size_t)NN * sizeof(float), stream);
  count_kernel<<<dim3((NE + 255) / 256), dim3(256), 0, stream>>>(dst, cnt);

  // conv1: 16 -> 32, mean, relu
  hipMemsetAsync(agg, 0, (size_t)NN * HID * sizeof(float), stream);
  nnconv_edges<IN, HID><<<egrid, eblk, 0, stream>>>(
      x, src, dst, ea, P(0, 0), P(0, 1), P(0, 2), P(0, 3), agg);
  finish_kernel<IN, HID, true, true><<<ngrid, nblk, 0, stream>>>(
      agg, cnt, x, P(0, 4), P(0, 5), h1);

  // conv2: 32 -> 32, mean, relu
  hipMemsetAsync(agg, 0, (size_t)NN * HID * sizeof(float), stream);
  nnconv_edges<HID, HID><<<egrid, eblk, 0, stream>>>(
      h1, src, dst, ea, P(1, 0), P(1, 1), P(1, 2), P(1, 3), agg);
  finish_kernel<HID, HID, true, true><<<ngrid, nblk, 0, stream>>>(
      agg, cnt, h1, P(1, 4), P(1, 5), h2);

  // cmu: 32 -> 16, no mean, no relu
  hipMemsetAsync(agg, 0, (size_t)NN * LAT * sizeof(float), stream);
  nnconv_edges<HID, LAT><<<egrid, eblk, 0, stream>>>(
      h2, src, dst, ea, P(2, 0), P(2, 1), P(2, 2), P(2, 3), agg);
  finish_kernel<HID, LAT, false, false><<<ngrid, nblk, 0, stream>>>(
      agg, cnt, h2, P(2, 4), P(2, 5), out_mu);

  // clv: 32 -> 16, no mean, no relu
  hipMemsetAsync(agg, 0, (size_t)NN * LAT * sizeof(float), stream);
  nnconv_edges<HID, LAT><<<egrid, eblk, 0, stream>>>(
      h2, src, dst, ea, P(3, 0), P(3, 1), P(3, 2), P(3, 3), agg);
  finish_kernel<HID, LAT, false, false><<<ngrid, nblk, 0, stream>>>(
      agg, cnt, h2, P(3, 4), P(3, 5), out_lv);
}